// Round 2
// baseline (1168.666 us; speedup 1.0000x reference)
//
#include <hip/hip_runtime.h>
#include <hip/hip_bf16.h>

#define N_NODES 100000
#define N_EDGES 3200000
#define IN_CH 128
#define HID 64
#define N_CLASSES 10

// ---------------- CSR build ----------------

__global__ void hist_k(const int* __restrict__ dst, int* __restrict__ deg) {
    int i = blockIdx.x * blockDim.x + threadIdx.x;
    int stride = gridDim.x * blockDim.x;
    for (int e = i; e < N_EDGES; e += stride) atomicAdd(&deg[dst[e]], 1);
}

// inclusive scan of 1024-chunks; off[i+1] = chunk-local inclusive, bsums[b] = chunk total
__global__ void scan1_k(const int* __restrict__ deg, int* __restrict__ off,
                        int* __restrict__ bsums) {
    __shared__ int s[1024];
    int chunk = blockIdx.x;
    int i = chunk * 1024 + threadIdx.x;
    int v = (i < N_NODES) ? deg[i] : 0;
    s[threadIdx.x] = v;
    __syncthreads();
    for (int o = 1; o < 1024; o <<= 1) {
        int t = (threadIdx.x >= o) ? s[threadIdx.x - o] : 0;
        __syncthreads();
        s[threadIdx.x] += t;
        __syncthreads();
    }
    if (i < N_NODES) off[i + 1] = s[threadIdx.x];
    if (threadIdx.x == 1023) bsums[chunk] = s[1023];
    if (i == 0) off[0] = 0;
}

__global__ void scan2_k(int* __restrict__ bsums, int nchunks) {
    __shared__ int s[128];
    int v = (threadIdx.x < nchunks) ? bsums[threadIdx.x] : 0;
    s[threadIdx.x] = v;
    __syncthreads();
    for (int o = 1; o < 128; o <<= 1) {
        int t = (threadIdx.x >= o) ? s[threadIdx.x - o] : 0;
        __syncthreads();
        s[threadIdx.x] += t;
        __syncthreads();
    }
    if (threadIdx.x < nchunks) bsums[threadIdx.x] = (threadIdx.x == 0) ? 0 : s[threadIdx.x - 1];
}

__global__ void scan3_k(int* __restrict__ off, const int* __restrict__ bsums) {
    int i = blockIdx.x * blockDim.x + threadIdx.x;
    if (i < N_NODES) off[i + 1] += bsums[i >> 10];
}

__global__ void fill_k(const int* __restrict__ src, const int* __restrict__ dst,
                       const int* __restrict__ off, int* __restrict__ cnt,
                       int* __restrict__ csr) {
    int i = blockIdx.x * blockDim.x + threadIdx.x;
    int stride = gridDim.x * blockDim.x;
    for (int e = i; e < N_EDGES; e += stride) {
        int d = dst[e];
        int p = atomicAdd(&cnt[d], 1);
        csr[off[d] + p] = src[e];
    }
}

// ---------------- aggregation (wave per node), fused "+ x" ----------------

// 128-channel: lane covers c and c+64
__global__ void aggA_k(const float* __restrict__ x, const int* __restrict__ off,
                       const int* __restrict__ csr, float* __restrict__ outv) {
    int wid = threadIdx.x >> 6, lane = threadIdx.x & 63;
    int n = blockIdx.x * 4 + wid;
    if (n >= N_NODES) return;
    float a0 = x[n * 128 + lane];
    float a1 = x[n * 128 + 64 + lane];
    int e0 = off[n], e1 = off[n + 1];
    for (int e = e0; e < e1; ++e) {
        int s = csr[e];
        a0 += x[s * 128 + lane];
        a1 += x[s * 128 + 64 + lane];
    }
    outv[n * 128 + lane] = a0;
    outv[n * 128 + 64 + lane] = a1;
}

// 64-channel
__global__ void aggB_k(const float* __restrict__ h, const int* __restrict__ off,
                       const int* __restrict__ csr, float* __restrict__ outv) {
    int wid = threadIdx.x >> 6, lane = threadIdx.x & 63;
    int n = blockIdx.x * 4 + wid;
    if (n >= N_NODES) return;
    float a = h[n * 64 + lane];
    int e0 = off[n], e1 = off[n + 1];
    for (int e = e0; e < e1; ++e) {
        int s = csr[e];
        a += h[s * 64 + lane];
    }
    outv[n * 64 + lane] = a;
}

// ---------------- MLP: relu(in @ W1 + b1) @ W2 + b2, then relu ----------------
// lane = output channel (HID==64==wave), wave handles 2 nodes per iteration.

template <int IN>
__global__ void mlp_k(const float* __restrict__ in, const float* __restrict__ W1,
                      const float* __restrict__ b1, const float* __restrict__ W2,
                      const float* __restrict__ b2, float* __restrict__ out) {
    __shared__ float sW1[IN * 64];
    __shared__ float sW2[64 * 64];
    __shared__ float sb1[64], sb2[64];
    __shared__ float srow[4][2][IN];
    __shared__ float sh[4][2][64];
    for (int i = threadIdx.x; i < IN * 64; i += 256) sW1[i] = W1[i];
    for (int i = threadIdx.x; i < 64 * 64; i += 256) sW2[i] = W2[i];
    if (threadIdx.x < 64) { sb1[threadIdx.x] = b1[threadIdx.x]; sb2[threadIdx.x] = b2[threadIdx.x]; }
    __syncthreads();
    int wid = threadIdx.x >> 6, lane = threadIdx.x & 63;
    int gw = blockIdx.x * 4 + wid;      // global wave id
    int nw = gridDim.x * 4;             // total waves
    for (int n = gw * 2; n < N_NODES; n += nw * 2) {
        // stage 2 node rows (N_NODES even, so n+1 always valid)
        srow[wid][0][lane] = in[(size_t)n * IN + lane];
        srow[wid][1][lane] = in[(size_t)(n + 1) * IN + lane];
        if (IN == 128) {
            srow[wid][0][64 + lane] = in[(size_t)n * IN + 64 + lane];
            srow[wid][1][64 + lane] = in[(size_t)(n + 1) * IN + 64 + lane];
        }
        float acc0 = sb1[lane], acc1 = sb1[lane];
#pragma unroll 8
        for (int c4 = 0; c4 < IN; c4 += 4) {
            float4 r0 = *(const float4*)&srow[wid][0][c4];
            float4 r1 = *(const float4*)&srow[wid][1][c4];
#pragma unroll
            for (int k = 0; k < 4; ++k) {
                float w = sW1[(c4 + k) * 64 + lane];
                acc0 = fmaf(((const float*)&r0)[k], w, acc0);
                acc1 = fmaf(((const float*)&r1)[k], w, acc1);
            }
        }
        sh[wid][0][lane] = fmaxf(acc0, 0.f);
        sh[wid][1][lane] = fmaxf(acc1, 0.f);
        float o0 = sb2[lane], o1 = sb2[lane];
#pragma unroll 8
        for (int j4 = 0; j4 < 64; j4 += 4) {
            float4 h0 = *(const float4*)&sh[wid][0][j4];
            float4 h1 = *(const float4*)&sh[wid][1][j4];
#pragma unroll
            for (int k = 0; k < 4; ++k) {
                float w = sW2[(j4 + k) * 64 + lane];
                o0 = fmaf(((const float*)&h0)[k], w, o0);
                o1 = fmaf(((const float*)&h1)[k], w, o1);
            }
        }
        out[(size_t)n * 64 + lane] = fmaxf(o0, 0.f);       // trailing inter-layer relu
        out[(size_t)(n + 1) * 64 + lane] = fmaxf(o1, 0.f);
    }
}

// ---------------- classifier + log_softmax ----------------

__global__ void cls_k(const float* __restrict__ h, const float* __restrict__ Wl,
                      const float* __restrict__ bl, float* __restrict__ out) {
    __shared__ float sW[64 * N_CLASSES];
    __shared__ float sb[16];
    for (int i = threadIdx.x; i < 64 * N_CLASSES; i += 256) sW[i] = Wl[i];
    if (threadIdx.x < N_CLASSES) sb[threadIdx.x] = bl[threadIdx.x];
    __syncthreads();
    int n = blockIdx.x * 256 + threadIdx.x;
    if (n >= N_NODES) return;
    float logit[N_CLASSES];
#pragma unroll
    for (int k = 0; k < N_CLASSES; ++k) logit[k] = sb[k];
    const float* row = h + (size_t)n * 64;
    for (int c = 0; c < 64; ++c) {
        float v = row[c];
#pragma unroll
        for (int k = 0; k < N_CLASSES; ++k) logit[k] = fmaf(v, sW[c * N_CLASSES + k], logit[k]);
    }
    float m = logit[0];
#pragma unroll
    for (int k = 1; k < N_CLASSES; ++k) m = fmaxf(m, logit[k]);
    float s = 0.f;
#pragma unroll
    for (int k = 0; k < N_CLASSES; ++k) s = s + __expf(logit[k] - m);
    float ls = __logf(s);
#pragma unroll
    for (int k = 0; k < N_CLASSES; ++k) out[(size_t)n * N_CLASSES + k] = logit[k] - m - ls;
}

// ---------------- launch ----------------

extern "C" void kernel_launch(void* const* d_in, const int* in_sizes, int n_in,
                              void* d_out, int out_size, void* d_ws, size_t ws_size,
                              hipStream_t stream) {
    const float* x   = (const float*)d_in[0];
    const int*   ei  = (const int*)d_in[1];
    const int*   src = ei;
    const int*   dst = ei + N_EDGES;
    const float* W1a = (const float*)d_in[2];
    const float* b1a = (const float*)d_in[3];
    const float* W2a = (const float*)d_in[4];
    const float* b2a = (const float*)d_in[5];
    const float* W1b = (const float*)d_in[6];
    const float* b1b = (const float*)d_in[7];
    const float* W2b = (const float*)d_in[8];
    const float* b2b = (const float*)d_in[9];
    const float* Wl  = (const float*)d_in[10];
    const float* bl  = (const float*)d_in[11];
    float* out = (float*)d_out;

    char* ws = (char*)d_ws;
    size_t o = 0;
    auto alloc = [&](size_t bytes) -> void* {
        o = (o + 255) & ~(size_t)255;
        void* p = ws + o;
        o += bytes;
        return p;
    };
    int* deg   = (int*)alloc((size_t)(N_NODES + 1) * 4);
    int* cnt   = (int*)alloc((size_t)N_NODES * 4);
    int* off   = (int*)alloc((size_t)(N_NODES + 1) * 4);
    int* bsums = (int*)alloc(128 * 4);
    int* csr   = (int*)alloc((size_t)N_EDGES * 4);
    float* h1  = (float*)alloc((size_t)N_NODES * 64 * 4);
    float* big = (float*)alloc((size_t)N_NODES * 128 * 4); // axin; later split as ah2|h2
    float* axin = big;
    float* ah2  = big;                       // reuse after axin is dead
    float* h2   = big + (size_t)N_NODES * 64;

    hipMemsetAsync(deg, 0, (size_t)N_NODES * 4, stream);
    hipMemsetAsync(cnt, 0, (size_t)N_NODES * 4, stream);

    const int nchunks = (N_NODES + 1023) / 1024; // 98
    hist_k <<<2048, 256, 0, stream>>>(dst, deg);
    scan1_k<<<nchunks, 1024, 0, stream>>>(deg, off, bsums);
    scan2_k<<<1, 128, 0, stream>>>(bsums, nchunks);
    scan3_k<<<(N_NODES + 255) / 256, 256, 0, stream>>>(off, bsums);
    fill_k <<<2048, 256, 0, stream>>>(src, dst, off, cnt, csr);

    aggA_k<<<(N_NODES + 3) / 4, 256, 0, stream>>>(x, off, csr, axin);
    mlp_k<128><<<2048, 256, 0, stream>>>(axin, W1a, b1a, W2a, b2a, h1);
    aggB_k<<<(N_NODES + 3) / 4, 256, 0, stream>>>(h1, off, csr, ah2);
    mlp_k<64><<<2048, 256, 0, stream>>>(ah2, W1b, b1b, W2b, b2b, h2);
    cls_k<<<(N_NODES + 255) / 256, 256, 0, stream>>>(h2, Wl, bl, out);
}

// Round 3
// 858.212 us; speedup vs baseline: 1.3617x; 1.3617x over previous
//
#include <hip/hip_runtime.h>
#include <hip/hip_bf16.h>

#define N_NODES 100000
#define N_EDGES 3200000
#define IN_CH 128
#define HID 64
#define N_CLASSES 10

typedef unsigned short u16;
typedef unsigned int u32;

static __device__ __forceinline__ float bf2f(u16 u) {
    union { u32 i; float f; } v; v.i = ((u32)u) << 16; return v.f;
}
static __device__ __forceinline__ u16 f2bf(float f) {
    __hip_bfloat16 b = __float2bfloat16(f);   // RNE
    return *(u16*)&b;
}

// ---------------- CSR build ----------------

__global__ void hist_k(const int* __restrict__ dst, int* __restrict__ deg) {
    int i = blockIdx.x * blockDim.x + threadIdx.x;
    int stride = gridDim.x * blockDim.x;
    for (int e = i; e < N_EDGES; e += stride) atomicAdd(&deg[dst[e]], 1);
}

__global__ void scan1_k(const int* __restrict__ deg, int* __restrict__ off,
                        int* __restrict__ bsums) {
    __shared__ int s[1024];
    int chunk = blockIdx.x;
    int i = chunk * 1024 + threadIdx.x;
    int v = (i < N_NODES) ? deg[i] : 0;
    s[threadIdx.x] = v;
    __syncthreads();
    for (int o = 1; o < 1024; o <<= 1) {
        int t = (threadIdx.x >= o) ? s[threadIdx.x - o] : 0;
        __syncthreads();
        s[threadIdx.x] += t;
        __syncthreads();
    }
    if (i < N_NODES) off[i + 1] = s[threadIdx.x];
    if (threadIdx.x == 1023) bsums[chunk] = s[1023];
    if (i == 0) off[0] = 0;
}

__global__ void scan2_k(int* __restrict__ bsums, int nchunks) {
    __shared__ int s[128];
    int v = (threadIdx.x < nchunks) ? bsums[threadIdx.x] : 0;
    s[threadIdx.x] = v;
    __syncthreads();
    for (int o = 1; o < 128; o <<= 1) {
        int t = (threadIdx.x >= o) ? s[threadIdx.x - o] : 0;
        __syncthreads();
        s[threadIdx.x] += t;
        __syncthreads();
    }
    if (threadIdx.x < nchunks) bsums[threadIdx.x] = (threadIdx.x == 0) ? 0 : s[threadIdx.x - 1];
}

__global__ void scan3_k(int* __restrict__ off, const int* __restrict__ bsums) {
    int i = blockIdx.x * blockDim.x + threadIdx.x;
    if (i < N_NODES) off[i + 1] += bsums[i >> 10];
}

__global__ void fill_k(const int* __restrict__ src, const int* __restrict__ dst,
                       const int* __restrict__ off, int* __restrict__ cnt,
                       int* __restrict__ csr) {
    int i = blockIdx.x * blockDim.x + threadIdx.x;
    int stride = gridDim.x * blockDim.x;
    for (int e = i; e < N_EDGES; e += stride) {
        int d = dst[e];
        int p = atomicAdd(&cnt[d], 1);
        csr[off[d] + p] = src[e];
    }
}

// ---------------- y = x @ W1a  (no bias), stored bf16 ----------------
// 512 threads = 8 waves; wave per node (grid-stride); lane = out channel.

__global__ void lin1_k(const float* __restrict__ x, const float* __restrict__ W1,
                       u16* __restrict__ yb) {
    __shared__ float sW[IN_CH * 64];      // 32 KB
    __shared__ float srow[8][IN_CH];      // 4 KB
    for (int i = threadIdx.x; i < IN_CH * 64; i += 512) sW[i] = W1[i];
    __syncthreads();
    int wid = threadIdx.x >> 6, lane = threadIdx.x & 63;
    int gw = blockIdx.x * 8 + wid;
    const int NW = 1024 * 8;
    for (int n = gw; n < N_NODES; n += NW) {
        srow[wid][lane]      = x[(size_t)n * IN_CH + lane];
        srow[wid][64 + lane] = x[(size_t)n * IN_CH + 64 + lane];
        __builtin_amdgcn_wave_barrier();
        float acc = 0.f;
#pragma unroll 8
        for (int c4 = 0; c4 < IN_CH; c4 += 4) {
            float4 r = *(const float4*)&srow[wid][c4];
            acc = fmaf(r.x, sW[(c4 + 0) * 64 + lane], acc);
            acc = fmaf(r.y, sW[(c4 + 1) * 64 + lane], acc);
            acc = fmaf(r.z, sW[(c4 + 2) * 64 + lane], acc);
            acc = fmaf(r.w, sW[(c4 + 3) * 64 + lane], acc);
        }
        __builtin_amdgcn_wave_barrier();
        yb[(size_t)n * 64 + lane] = f2bf(acc);
    }
}

// ---------------- layer A fused: agg(y) -> +b1,relu -> @W2a+b2a -> relu -> h1 bf16
// wave per node; gather bf16 rows (128 B/edge), f32 accumulate.

__global__ void aggFA_k(const u16* __restrict__ yb, const int* __restrict__ off,
                        const int* __restrict__ csr, const float* __restrict__ b1,
                        const float* __restrict__ W2, const float* __restrict__ b2,
                        u16* __restrict__ h1b) {
    __shared__ float sW[64 * 64];         // 16 KB
    __shared__ float su[8][64];           // 2 KB
    for (int i = threadIdx.x; i < 64 * 64; i += 512) sW[i] = W2[i];
    __syncthreads();
    int wid = threadIdx.x >> 6, lane = threadIdx.x & 63;
    float bb1 = b1[lane], bb2 = b2[lane];
    int gw = blockIdx.x * 8 + wid;
    const int NW = 1024 * 8;
    for (int n = gw; n < N_NODES; n += NW) {
        float a0 = bf2f(yb[(size_t)n * 64 + lane]);   // self term
        float a1 = 0.f;
        int e = off[n], e1 = off[n + 1];
        for (; e + 1 < e1; e += 2) {
            int s0 = csr[e], s1 = csr[e + 1];
            a0 += bf2f(yb[(size_t)s0 * 64 + lane]);
            a1 += bf2f(yb[(size_t)s1 * 64 + lane]);
        }
        if (e < e1) a0 += bf2f(yb[(size_t)csr[e] * 64 + lane]);
        float u = fmaxf(a0 + a1 + bb1, 0.f);
        su[wid][lane] = u;
        __builtin_amdgcn_wave_barrier();
        float o = bb2;
#pragma unroll 8
        for (int c = 0; c < 64; ++c) o = fmaf(su[wid][c], sW[c * 64 + lane], o);
        __builtin_amdgcn_wave_barrier();
        h1b[(size_t)n * 64 + lane] = f2bf(fmaxf(o, 0.f));   // inter-layer relu
    }
}

// ---------------- layer B fused: agg(h1) -> @W1b+b1b,relu -> @W2b+b2b -> relu -> h2 bf16

__global__ void aggFB_k(const u16* __restrict__ h1b, const int* __restrict__ off,
                        const int* __restrict__ csr, const float* __restrict__ W1,
                        const float* __restrict__ b1, const float* __restrict__ W2,
                        const float* __restrict__ b2, u16* __restrict__ h2b) {
    __shared__ float sW1[64 * 64];        // 16 KB
    __shared__ float sW2[64 * 64];        // 16 KB
    __shared__ float sv[8][64];           // 2 KB
    __shared__ float su[8][64];           // 2 KB
    for (int i = threadIdx.x; i < 64 * 64; i += 512) { sW1[i] = W1[i]; sW2[i] = W2[i]; }
    __syncthreads();
    int wid = threadIdx.x >> 6, lane = threadIdx.x & 63;
    float bb1 = b1[lane], bb2 = b2[lane];
    int gw = blockIdx.x * 8 + wid;
    const int NW = 1024 * 8;
    for (int n = gw; n < N_NODES; n += NW) {
        float a0 = bf2f(h1b[(size_t)n * 64 + lane]);  // self term
        float a1 = 0.f;
        int e = off[n], e1 = off[n + 1];
        for (; e + 1 < e1; e += 2) {
            int s0 = csr[e], s1 = csr[e + 1];
            a0 += bf2f(h1b[(size_t)s0 * 64 + lane]);
            a1 += bf2f(h1b[(size_t)s1 * 64 + lane]);
        }
        if (e < e1) a0 += bf2f(h1b[(size_t)csr[e] * 64 + lane]);
        sv[wid][lane] = a0 + a1;
        __builtin_amdgcn_wave_barrier();
        float u = bb1;
#pragma unroll 8
        for (int c = 0; c < 64; ++c) u = fmaf(sv[wid][c], sW1[c * 64 + lane], u);
        u = fmaxf(u, 0.f);
        __builtin_amdgcn_wave_barrier();
        su[wid][lane] = u;
        __builtin_amdgcn_wave_barrier();
        float o = bb2;
#pragma unroll 8
        for (int c = 0; c < 64; ++c) o = fmaf(su[wid][c], sW2[c * 64 + lane], o);
        __builtin_amdgcn_wave_barrier();
        h2b[(size_t)n * 64 + lane] = f2bf(fmaxf(o, 0.f));   // outer relu
    }
}

// ---------------- classifier + log_softmax (thread per node, bf16 input) ----------------

__global__ void cls_k(const u16* __restrict__ h2b, const float* __restrict__ Wl,
                      const float* __restrict__ bl, float* __restrict__ out) {
    __shared__ float sW[64 * N_CLASSES];
    __shared__ float sb[16];
    for (int i = threadIdx.x; i < 64 * N_CLASSES; i += 256) sW[i] = Wl[i];
    if (threadIdx.x < N_CLASSES) sb[threadIdx.x] = bl[threadIdx.x];
    __syncthreads();
    int n = blockIdx.x * 256 + threadIdx.x;
    if (n >= N_NODES) return;
    float logit[N_CLASSES];
#pragma unroll
    for (int k = 0; k < N_CLASSES; ++k) logit[k] = sb[k];
    const ushort4* row = (const ushort4*)(h2b + (size_t)n * 64);
#pragma unroll
    for (int i = 0; i < 16; ++i) {
        ushort4 q = row[i];
        float v0 = bf2f(q.x), v1 = bf2f(q.y), v2 = bf2f(q.z), v3 = bf2f(q.w);
#pragma unroll
        for (int k = 0; k < N_CLASSES; ++k) {
            logit[k] = fmaf(v0, sW[(i * 4 + 0) * N_CLASSES + k], logit[k]);
            logit[k] = fmaf(v1, sW[(i * 4 + 1) * N_CLASSES + k], logit[k]);
            logit[k] = fmaf(v2, sW[(i * 4 + 2) * N_CLASSES + k], logit[k]);
            logit[k] = fmaf(v3, sW[(i * 4 + 3) * N_CLASSES + k], logit[k]);
        }
    }
    float m = logit[0];
#pragma unroll
    for (int k = 1; k < N_CLASSES; ++k) m = fmaxf(m, logit[k]);
    float s = 0.f;
#pragma unroll
    for (int k = 0; k < N_CLASSES; ++k) s = s + __expf(logit[k] - m);
    float ls = __logf(s);
#pragma unroll
    for (int k = 0; k < N_CLASSES; ++k) out[(size_t)n * N_CLASSES + k] = logit[k] - m - ls;
}

// ---------------- launch ----------------

extern "C" void kernel_launch(void* const* d_in, const int* in_sizes, int n_in,
                              void* d_out, int out_size, void* d_ws, size_t ws_size,
                              hipStream_t stream) {
    const float* x   = (const float*)d_in[0];
    const int*   ei  = (const int*)d_in[1];
    const int*   src = ei;
    const int*   dst = ei + N_EDGES;
    const float* W1a = (const float*)d_in[2];
    const float* b1a = (const float*)d_in[3];
    const float* W2a = (const float*)d_in[4];
    const float* b2a = (const float*)d_in[5];
    const float* W1b = (const float*)d_in[6];
    const float* b1b = (const float*)d_in[7];
    const float* W2b = (const float*)d_in[8];
    const float* b2b = (const float*)d_in[9];
    const float* Wl  = (const float*)d_in[10];
    const float* bl  = (const float*)d_in[11];
    float* out = (float*)d_out;

    char* ws = (char*)d_ws;
    size_t o = 0;
    auto alloc = [&](size_t bytes) -> void* {
        o = (o + 255) & ~(size_t)255;
        void* p = ws + o;
        o += bytes;
        return p;
    };
    int* deg   = (int*)alloc((size_t)(N_NODES + 1) * 4);
    int* cnt   = (int*)alloc((size_t)N_NODES * 4);
    int* off   = (int*)alloc((size_t)(N_NODES + 1) * 4);
    int* bsums = (int*)alloc(128 * 4);
    int* csr   = (int*)alloc((size_t)N_EDGES * 4);
    u16* yb    = (u16*)alloc((size_t)N_NODES * 64 * 2);
    u16* h1b   = (u16*)alloc((size_t)N_NODES * 64 * 2);
    u16* h2b   = (u16*)alloc((size_t)N_NODES * 64 * 2);

    hipMemsetAsync(deg, 0, (size_t)N_NODES * 4, stream);
    hipMemsetAsync(cnt, 0, (size_t)N_NODES * 4, stream);

    const int nchunks = (N_NODES + 1023) / 1024; // 98
    hist_k <<<2048, 256, 0, stream>>>(dst, deg);
    scan1_k<<<nchunks, 1024, 0, stream>>>(deg, off, bsums);
    scan2_k<<<1, 128, 0, stream>>>(bsums, nchunks);
    scan3_k<<<(N_NODES + 255) / 256, 256, 0, stream>>>(off, bsums);
    fill_k <<<2048, 256, 0, stream>>>(src, dst, off, cnt, csr);

    lin1_k <<<1024, 512, 0, stream>>>(x, W1a, yb);
    aggFA_k<<<1024, 512, 0, stream>>>(yb, off, csr, b1a, W2a, b2a, h1b);
    aggFB_k<<<1024, 512, 0, stream>>>(h1b, off, csr, W1b, b1b, W2b, b2b, h2b);
    cls_k  <<<(N_NODES + 255) / 256, 256, 0, stream>>>(h2b, Wl, bl, out);
}

// Round 4
// 559.019 us; speedup vs baseline: 2.0906x; 1.5352x over previous
//
#include <hip/hip_runtime.h>
#include <hip/hip_bf16.h>

#define N_NODES 100000
#define N_EDGES 3200000
#define IN_CH 128
#define HID 64
#define N_CLASSES 10

// bucketized CSR build
#define NB 391          // ceil(100000/256) buckets of 256 nodes
#define NPB 256         // nodes per bucket
#define BCAP 10240      // stage capacity per bucket (mean 8192, sigma~90 -> >20 sigma)
#define CHUNK 16384     // edges per passA block

typedef unsigned short u16;
typedef unsigned int u32;

static __device__ __forceinline__ float bf2f(u16 u) {
    union { u32 i; float f; } v; v.i = ((u32)u) << 16; return v.f;
}
static __device__ __forceinline__ u16 f2bf(float f) {
    __hip_bfloat16 b = __float2bfloat16(f);   // RNE
    return *(u16*)&b;
}

// ---------------- CSR build: pass A — bucket partition ----------------
// block: 1024 threads, CHUNK edges. LDS histogram -> global reservation ->
// scatter (src, dst_local) into per-bucket contiguous runs.

__global__ void __launch_bounds__(1024) passA_k(
        const int* __restrict__ src, const int* __restrict__ dst,
        int* __restrict__ bcnt, int2* __restrict__ stage) {
    __shared__ int lh[NB];   // local hist, then local cursor
    __shared__ int lb[NB];   // global base of this block's run per bucket
    for (int i = threadIdx.x; i < NB; i += 1024) lh[i] = 0;
    __syncthreads();
    int e0 = blockIdx.x * CHUNK;
#pragma unroll
    for (int k = 0; k < CHUNK / 1024; ++k) {
        int e = e0 + k * 1024 + threadIdx.x;
        if (e < N_EDGES) atomicAdd(&lh[dst[e] >> 8], 1);
    }
    __syncthreads();
    for (int i = threadIdx.x; i < NB; i += 1024) {
        lb[i] = atomicAdd(&bcnt[i], lh[i]);
        lh[i] = 0;
    }
    __syncthreads();
#pragma unroll
    for (int k = 0; k < CHUNK / 1024; ++k) {
        int e = e0 + k * 1024 + threadIdx.x;
        if (e < N_EDGES) {
            int d = dst[e];
            int b = d >> 8;
            int p = lb[b] + atomicAdd(&lh[b], 1);
            if (p < BCAP) stage[(size_t)b * BCAP + p] = make_int2(src[e], d & 255);
        }
    }
}

// ---------------- pass A.5 — scan bucket counts -> bucket csr bases ----------------

__global__ void bscan_k(const int* __restrict__ bcnt, int* __restrict__ bbase,
                        int* __restrict__ off) {
    __shared__ int s[512];
    int tid = threadIdx.x;
    int v = (tid < NB) ? min(bcnt[tid], BCAP) : 0;
    s[tid] = v;
    __syncthreads();
    for (int o = 1; o < 512; o <<= 1) {
        int t = (tid >= o) ? s[tid - o] : 0;
        __syncthreads();
        s[tid] += t;
        __syncthreads();
    }
    if (tid < NB) bbase[tid] = s[tid] - v;       // exclusive
    if (tid == NB - 1) off[N_NODES] = s[tid];    // total staged edges
}

// ---------------- pass B — per-bucket CSR build in LDS, coalesced writeout ----------------

__global__ void __launch_bounds__(1024) passB_k(
        const int* __restrict__ bcnt, const int* __restrict__ bbase,
        const int2* __restrict__ stage, int* __restrict__ off,
        int* __restrict__ csr) {
    __shared__ int ldeg[NPB];
    __shared__ int loff[NPB + 1];
    __shared__ int lcur[NPB];
    __shared__ int img[BCAP];
    int b = blockIdx.x;
    int nb = min(bcnt[b], BCAP);
    int base = bbase[b];
    const int2* st = stage + (size_t)b * BCAP;
    int tid = threadIdx.x;
    if (tid < NPB) ldeg[tid] = 0;
    __syncthreads();
    for (int i = tid; i < nb; i += 1024) atomicAdd(&ldeg[st[i].y], 1);
    __syncthreads();
    // exclusive scan of ldeg[256] (Hillis-Steele in lcur)
    if (tid < NPB) lcur[tid] = ldeg[tid];
    __syncthreads();
    for (int o = 1; o < NPB; o <<= 1) {
        int t = (tid < NPB && tid >= o) ? lcur[tid - o] : 0;
        __syncthreads();
        if (tid < NPB) lcur[tid] += t;
        __syncthreads();
    }
    if (tid < NPB) loff[tid + 1] = lcur[tid];
    if (tid == 0) loff[0] = 0;
    __syncthreads();
    if (tid < NPB) {
        int gnode = (b << 8) + tid;
        if (gnode < N_NODES) off[gnode] = base + loff[tid];
        lcur[tid] = loff[tid];   // cursor = exclusive start
    }
    __syncthreads();
    for (int i = tid; i < nb; i += 1024) {
        int2 pr = st[i];
        int p = atomicAdd(&lcur[pr.y], 1);
        img[p] = pr.x;
    }
    __syncthreads();
    for (int i = tid; i < nb; i += 1024) csr[base + i] = img[i];
}

// ---------------- y = x @ W1a  (no bias), stored bf16 ----------------

__global__ void lin1_k(const float* __restrict__ x, const float* __restrict__ W1,
                       u16* __restrict__ yb) {
    __shared__ float sW[IN_CH * 64];      // 32 KB
    __shared__ float srow[8][IN_CH];      // 4 KB
    for (int i = threadIdx.x; i < IN_CH * 64; i += 512) sW[i] = W1[i];
    __syncthreads();
    int wid = threadIdx.x >> 6, lane = threadIdx.x & 63;
    int gw = blockIdx.x * 8 + wid;
    const int NW = 1024 * 8;
    for (int n = gw; n < N_NODES; n += NW) {
        srow[wid][lane]      = x[(size_t)n * IN_CH + lane];
        srow[wid][64 + lane] = x[(size_t)n * IN_CH + 64 + lane];
        __builtin_amdgcn_wave_barrier();
        float acc = 0.f;
#pragma unroll 8
        for (int c4 = 0; c4 < IN_CH; c4 += 4) {
            float4 r = *(const float4*)&srow[wid][c4];
            acc = fmaf(r.x, sW[(c4 + 0) * 64 + lane], acc);
            acc = fmaf(r.y, sW[(c4 + 1) * 64 + lane], acc);
            acc = fmaf(r.z, sW[(c4 + 2) * 64 + lane], acc);
            acc = fmaf(r.w, sW[(c4 + 3) * 64 + lane], acc);
        }
        __builtin_amdgcn_wave_barrier();
        yb[(size_t)n * 64 + lane] = f2bf(acc);
    }
}

// ---------------- layer A fused: agg(y) -> +b1,relu -> @W2a+b2a -> relu -> h1 bf16

__global__ void aggFA_k(const u16* __restrict__ yb, const int* __restrict__ off,
                        const int* __restrict__ csr, const float* __restrict__ b1,
                        const float* __restrict__ W2, const float* __restrict__ b2,
                        u16* __restrict__ h1b) {
    __shared__ float sW[64 * 64];         // 16 KB
    __shared__ float su[8][64];           // 2 KB
    for (int i = threadIdx.x; i < 64 * 64; i += 512) sW[i] = W2[i];
    __syncthreads();
    int wid = threadIdx.x >> 6, lane = threadIdx.x & 63;
    float bb1 = b1[lane], bb2 = b2[lane];
    int gw = blockIdx.x * 8 + wid;
    const int NW = 1024 * 8;
    for (int n = gw; n < N_NODES; n += NW) {
        float a0 = bf2f(yb[(size_t)n * 64 + lane]);   // self term
        float a1 = 0.f;
        int e = off[n], e1 = off[n + 1];
        for (; e + 1 < e1; e += 2) {
            int s0 = csr[e], s1 = csr[e + 1];
            a0 += bf2f(yb[(size_t)s0 * 64 + lane]);
            a1 += bf2f(yb[(size_t)s1 * 64 + lane]);
        }
        if (e < e1) a0 += bf2f(yb[(size_t)csr[e] * 64 + lane]);
        float u = fmaxf(a0 + a1 + bb1, 0.f);
        su[wid][lane] = u;
        __builtin_amdgcn_wave_barrier();
        float o = bb2;
#pragma unroll 8
        for (int c = 0; c < 64; ++c) o = fmaf(su[wid][c], sW[c * 64 + lane], o);
        __builtin_amdgcn_wave_barrier();
        h1b[(size_t)n * 64 + lane] = f2bf(fmaxf(o, 0.f));   // inter-layer relu
    }
}

// ---------------- layer B fused: agg(h1) -> @W1b+b1b,relu -> @W2b+b2b -> relu -> h2 bf16

__global__ void aggFB_k(const u16* __restrict__ h1b, const int* __restrict__ off,
                        const int* __restrict__ csr, const float* __restrict__ W1,
                        const float* __restrict__ b1, const float* __restrict__ W2,
                        const float* __restrict__ b2, u16* __restrict__ h2b) {
    __shared__ float sW1[64 * 64];
    __shared__ float sW2[64 * 64];
    __shared__ float sv[8][64];
    __shared__ float su[8][64];
    for (int i = threadIdx.x; i < 64 * 64; i += 512) { sW1[i] = W1[i]; sW2[i] = W2[i]; }
    __syncthreads();
    int wid = threadIdx.x >> 6, lane = threadIdx.x & 63;
    float bb1 = b1[lane], bb2 = b2[lane];
    int gw = blockIdx.x * 8 + wid;
    const int NW = 1024 * 8;
    for (int n = gw; n < N_NODES; n += NW) {
        float a0 = bf2f(h1b[(size_t)n * 64 + lane]);  // self term
        float a1 = 0.f;
        int e = off[n], e1 = off[n + 1];
        for (; e + 1 < e1; e += 2) {
            int s0 = csr[e], s1 = csr[e + 1];
            a0 += bf2f(h1b[(size_t)s0 * 64 + lane]);
            a1 += bf2f(h1b[(size_t)s1 * 64 + lane]);
        }
        if (e < e1) a0 += bf2f(h1b[(size_t)csr[e] * 64 + lane]);
        sv[wid][lane] = a0 + a1;
        __builtin_amdgcn_wave_barrier();
        float u = bb1;
#pragma unroll 8
        for (int c = 0; c < 64; ++c) u = fmaf(sv[wid][c], sW1[c * 64 + lane], u);
        u = fmaxf(u, 0.f);
        __builtin_amdgcn_wave_barrier();
        su[wid][lane] = u;
        __builtin_amdgcn_wave_barrier();
        float o = bb2;
#pragma unroll 8
        for (int c = 0; c < 64; ++c) o = fmaf(su[wid][c], sW2[c * 64 + lane], o);
        __builtin_amdgcn_wave_barrier();
        h2b[(size_t)n * 64 + lane] = f2bf(fmaxf(o, 0.f));   // outer relu
    }
}

// ---------------- classifier + log_softmax ----------------

__global__ void cls_k(const u16* __restrict__ h2b, const float* __restrict__ Wl,
                      const float* __restrict__ bl, float* __restrict__ out) {
    __shared__ float sW[64 * N_CLASSES];
    __shared__ float sb[16];
    for (int i = threadIdx.x; i < 64 * N_CLASSES; i += 256) sW[i] = Wl[i];
    if (threadIdx.x < N_CLASSES) sb[threadIdx.x] = bl[threadIdx.x];
    __syncthreads();
    int n = blockIdx.x * 256 + threadIdx.x;
    if (n >= N_NODES) return;
    float logit[N_CLASSES];
#pragma unroll
    for (int k = 0; k < N_CLASSES; ++k) logit[k] = sb[k];
    const ushort4* row = (const ushort4*)(h2b + (size_t)n * 64);
#pragma unroll
    for (int i = 0; i < 16; ++i) {
        ushort4 q = row[i];
        float v0 = bf2f(q.x), v1 = bf2f(q.y), v2 = bf2f(q.z), v3 = bf2f(q.w);
#pragma unroll
        for (int k = 0; k < N_CLASSES; ++k) {
            logit[k] = fmaf(v0, sW[(i * 4 + 0) * N_CLASSES + k], logit[k]);
            logit[k] = fmaf(v1, sW[(i * 4 + 1) * N_CLASSES + k], logit[k]);
            logit[k] = fmaf(v2, sW[(i * 4 + 2) * N_CLASSES + k], logit[k]);
            logit[k] = fmaf(v3, sW[(i * 4 + 3) * N_CLASSES + k], logit[k]);
        }
    }
    float m = logit[0];
#pragma unroll
    for (int k = 1; k < N_CLASSES; ++k) m = fmaxf(m, logit[k]);
    float s = 0.f;
#pragma unroll
    for (int k = 0; k < N_CLASSES; ++k) s = s + __expf(logit[k] - m);
    float ls = __logf(s);
#pragma unroll
    for (int k = 0; k < N_CLASSES; ++k) out[(size_t)n * N_CLASSES + k] = logit[k] - m - ls;
}

// ---------------- launch ----------------

extern "C" void kernel_launch(void* const* d_in, const int* in_sizes, int n_in,
                              void* d_out, int out_size, void* d_ws, size_t ws_size,
                              hipStream_t stream) {
    const float* x   = (const float*)d_in[0];
    const int*   ei  = (const int*)d_in[1];
    const int*   src = ei;
    const int*   dst = ei + N_EDGES;
    const float* W1a = (const float*)d_in[2];
    const float* b1a = (const float*)d_in[3];
    const float* W2a = (const float*)d_in[4];
    const float* b2a = (const float*)d_in[5];
    const float* W1b = (const float*)d_in[6];
    const float* b1b = (const float*)d_in[7];
    const float* W2b = (const float*)d_in[8];
    const float* b2b = (const float*)d_in[9];
    const float* Wl  = (const float*)d_in[10];
    const float* bl  = (const float*)d_in[11];
    float* out = (float*)d_out;

    char* ws = (char*)d_ws;
    size_t o = 0;
    auto alloc = [&](size_t bytes) -> void* {
        o = (o + 255) & ~(size_t)255;
        void* p = ws + o;
        o += bytes;
        return p;
    };
    int*  bcnt  = (int*)alloc((size_t)NB * 4);
    int*  bbase = (int*)alloc((size_t)NB * 4);
    int*  off   = (int*)alloc((size_t)(N_NODES + 1) * 4);
    int2* stage = (int2*)alloc((size_t)NB * BCAP * 8);     // 32.0 MB
    int*  csr   = (int*)alloc((size_t)N_EDGES * 4);        // 12.8 MB
    u16*  yb    = (u16*)alloc((size_t)N_NODES * 64 * 2);   // 12.8 MB
    u16*  h1b   = (u16*)alloc((size_t)N_NODES * 64 * 2);
    u16*  h2b   = (u16*)alloc((size_t)N_NODES * 64 * 2);

    hipMemsetAsync(bcnt, 0, (size_t)NB * 4, stream);

    const int nA = (N_EDGES + CHUNK - 1) / CHUNK;          // 196
    passA_k<<<nA, 1024, 0, stream>>>(src, dst, bcnt, stage);
    bscan_k<<<1, 512, 0, stream>>>(bcnt, bbase, off);
    passB_k<<<NB, 1024, 0, stream>>>(bcnt, bbase, stage, off, csr);

    lin1_k <<<1024, 512, 0, stream>>>(x, W1a, yb);
    aggFA_k<<<1024, 512, 0, stream>>>(yb, off, csr, b1a, W2a, b2a, h1b);
    aggFB_k<<<1024, 512, 0, stream>>>(h1b, off, csr, W1b, b1b, W2b, b2b, h2b);
    cls_k  <<<(N_NODES + 255) / 256, 256, 0, stream>>>(h2b, Wl, bl, out);
}

// Round 5
// 406.493 us; speedup vs baseline: 2.8750x; 1.3752x over previous
//
#include <hip/hip_runtime.h>
#include <hip/hip_bf16.h>

#define N_NODES 100000
#define N_EDGES 3200000
#define IN_CH 128
#define HID 64
#define N_CLASSES 10

// bucketized CSR build
#define NB 391          // ceil(100000/256) buckets of 256 nodes
#define NPB 256
#define BCAP 10240      // mean 8192, sigma~90
#define CHUNK 16384

typedef unsigned short u16;
typedef unsigned int u32;

static __device__ __forceinline__ float u2f(u32 u) {
    union { u32 i; float f; } v; v.i = u; return v.f;
}
static __device__ __forceinline__ u16 f2bf(float f) {
    __hip_bfloat16 b = __float2bfloat16(f);   // RNE
    return *(u16*)&b;
}

// ---------------- CSR build: pass A — bucket partition (packed u32 stage) ----------------

__global__ void __launch_bounds__(1024) passA_k(
        const int* __restrict__ src, const int* __restrict__ dst,
        int* __restrict__ bcnt, u32* __restrict__ stage) {
    __shared__ int lh[NB];
    __shared__ int lb[NB];
    for (int i = threadIdx.x; i < NB; i += 1024) lh[i] = 0;
    __syncthreads();
    int e0 = blockIdx.x * CHUNK;
#pragma unroll
    for (int k = 0; k < CHUNK / 1024; ++k) {
        int e = e0 + k * 1024 + threadIdx.x;
        if (e < N_EDGES) atomicAdd(&lh[dst[e] >> 8], 1);
    }
    __syncthreads();
    for (int i = threadIdx.x; i < NB; i += 1024) {
        lb[i] = atomicAdd(&bcnt[i], lh[i]);
        lh[i] = 0;
    }
    __syncthreads();
#pragma unroll
    for (int k = 0; k < CHUNK / 1024; ++k) {
        int e = e0 + k * 1024 + threadIdx.x;
        if (e < N_EDGES) {
            int d = dst[e];
            int b = d >> 8;
            int p = lb[b] + atomicAdd(&lh[b], 1);
            if (p < BCAP) stage[(size_t)b * BCAP + p] = ((u32)src[e] << 8) | (u32)(d & 255);
        }
    }
}

// ---------------- bucket scan ----------------

__global__ void bscan_k(const int* __restrict__ bcnt, int* __restrict__ bbase,
                        int* __restrict__ off) {
    __shared__ int s[512];
    int tid = threadIdx.x;
    int v = (tid < NB) ? min(bcnt[tid], BCAP) : 0;
    s[tid] = v;
    __syncthreads();
    for (int o = 1; o < 512; o <<= 1) {
        int t = (tid >= o) ? s[tid - o] : 0;
        __syncthreads();
        s[tid] += t;
        __syncthreads();
    }
    if (tid < NB) bbase[tid] = s[tid] - v;
    if (tid == NB - 1) off[N_NODES] = s[tid];
}

// ---------------- pass B — per-bucket CSR in LDS, coalesced writeout ----------------

__global__ void __launch_bounds__(1024) passB_k(
        const int* __restrict__ bcnt, const int* __restrict__ bbase,
        const u32* __restrict__ stage, int* __restrict__ off,
        int* __restrict__ csr) {
    __shared__ int ldeg[NPB];
    __shared__ int loff[NPB + 1];
    __shared__ int lcur[NPB];
    __shared__ int img[BCAP];
    int b = blockIdx.x;
    int nb = min(bcnt[b], BCAP);
    int base = bbase[b];
    const u32* st = stage + (size_t)b * BCAP;
    int tid = threadIdx.x;
    if (tid < NPB) ldeg[tid] = 0;
    __syncthreads();
    for (int i = tid; i < nb; i += 1024) atomicAdd(&ldeg[st[i] & 255u], 1);
    __syncthreads();
    if (tid < NPB) lcur[tid] = ldeg[tid];
    __syncthreads();
    for (int o = 1; o < NPB; o <<= 1) {
        int t = (tid < NPB && tid >= o) ? lcur[tid - o] : 0;
        __syncthreads();
        if (tid < NPB) lcur[tid] += t;
        __syncthreads();
    }
    if (tid < NPB) loff[tid + 1] = lcur[tid];
    if (tid == 0) loff[0] = 0;
    __syncthreads();
    if (tid < NPB) {
        int gnode = (b << 8) + tid;
        if (gnode < N_NODES) off[gnode] = base + loff[tid];
        lcur[tid] = loff[tid];
    }
    __syncthreads();
    for (int i = tid; i < nb; i += 1024) {
        u32 pr = st[i];
        int p = atomicAdd(&lcur[pr & 255u], 1);
        img[p] = (int)(pr >> 8);
    }
    __syncthreads();
    for (int i = tid; i < nb; i += 1024) csr[base + i] = img[i];
}

// ---------------- y = x @ W1a  (no bias), stored bf16 ----------------

__global__ void lin1_k(const float* __restrict__ x, const float* __restrict__ W1,
                       u16* __restrict__ yb) {
    __shared__ __align__(16) float sW[IN_CH * 64];
    __shared__ __align__(16) float srow[8][IN_CH];
    for (int i = threadIdx.x; i < IN_CH * 64; i += 512) sW[i] = W1[i];
    __syncthreads();
    int wid = threadIdx.x >> 6, lane = threadIdx.x & 63;
    int gw = blockIdx.x * 8 + wid;
    const int NW = 1024 * 8;
    for (int n = gw; n < N_NODES; n += NW) {
        srow[wid][lane]      = x[(size_t)n * IN_CH + lane];
        srow[wid][64 + lane] = x[(size_t)n * IN_CH + 64 + lane];
        __builtin_amdgcn_wave_barrier();
        float acc = 0.f;
#pragma unroll 8
        for (int c4 = 0; c4 < IN_CH; c4 += 4) {
            float4 r = *(const float4*)&srow[wid][c4];
            acc = fmaf(r.x, sW[(c4 + 0) * 64 + lane], acc);
            acc = fmaf(r.y, sW[(c4 + 1) * 64 + lane], acc);
            acc = fmaf(r.z, sW[(c4 + 2) * 64 + lane], acc);
            acc = fmaf(r.w, sW[(c4 + 3) * 64 + lane], acc);
        }
        __builtin_amdgcn_wave_barrier();
        yb[(size_t)n * 64 + lane] = f2bf(acc);
    }
}

// swizzled weight fill: sW4[(c>>2)*256 + out*4 + (c&3)] = W[c*64+out]
static __device__ __forceinline__ void fill_swz(float* sW4, const float* __restrict__ W,
                                                int tid, int nthr) {
    for (int i = tid; i < 64 * 64; i += nthr) {
        int c = i >> 6, out = i & 63;
        sW4[((c >> 2) << 8) + (out << 2) + (c & 3)] = W[i];
    }
}

// 8-edge gather step: lane l -> edge slot g=l>>3, channel octet c=l&7.
#define AGG_BODY(TAB)                                                                   \
    const char* tb = (const char*)(TAB);                                                \
    int g = lane >> 3, c = lane & 7;                                                    \
    int coff = c << 4; /* byte offset in 128B row */                                    \
    float a0, a1, a2, a3, a4, a5, a6, a7;                                               \
    {   uint4 dS = *(const uint4*)(tb + (size_t)n * 128 + coff);                        \
        u32 sm = (g == 0) ? 0xffffffffu : 0u;                                           \
        dS.x &= sm; dS.y &= sm; dS.z &= sm; dS.w &= sm;                                 \
        a0 = u2f(dS.x << 16); a1 = u2f(dS.x & 0xffff0000u);                             \
        a2 = u2f(dS.y << 16); a3 = u2f(dS.y & 0xffff0000u);                             \
        a4 = u2f(dS.z << 16); a5 = u2f(dS.z & 0xffff0000u);                             \
        a6 = u2f(dS.w << 16); a7 = u2f(dS.w & 0xffff0000u); }                           \
    int e = off[n], e1 = off[n + 1];                                                    \
    int nfull = (e1 - e) >> 3;                                                          \
    _Pragma("unroll 2")                                                                 \
    for (int it = 0; it < nfull; ++it) {                                                \
        int s = csr[e + g];                                                             \
        uint4 d = *(const uint4*)(tb + (size_t)s * 128 + coff);                         \
        a0 += u2f(d.x << 16); a1 += u2f(d.x & 0xffff0000u);                             \
        a2 += u2f(d.y << 16); a3 += u2f(d.y & 0xffff0000u);                             \
        a4 += u2f(d.z << 16); a5 += u2f(d.z & 0xffff0000u);                             \
        a6 += u2f(d.w << 16); a7 += u2f(d.w & 0xffff0000u);                             \
        e += 8;                                                                         \
    }                                                                                   \
    int rem = e1 - e;                                                                   \
    if (rem > 0) {                                                                      \
        int s = csr[e + min(g, rem - 1)];                                               \
        u32 m = (g < rem) ? 0xffffffffu : 0u;                                           \
        uint4 d = *(const uint4*)(tb + (size_t)s * 128 + coff);                         \
        d.x &= m; d.y &= m; d.z &= m; d.w &= m;                                         \
        a0 += u2f(d.x << 16); a1 += u2f(d.x & 0xffff0000u);                             \
        a2 += u2f(d.y << 16); a3 += u2f(d.y & 0xffff0000u);                             \
        a4 += u2f(d.z << 16); a5 += u2f(d.z & 0xffff0000u);                             \
        a6 += u2f(d.w << 16); a7 += u2f(d.w & 0xffff0000u);                             \
    }                                                                                   \
    /* reduce across the 8 edge groups (xor 8,16,32) */                                 \
    a0 += __shfl_xor(a0, 8);  a1 += __shfl_xor(a1, 8);  a2 += __shfl_xor(a2, 8);        \
    a3 += __shfl_xor(a3, 8);  a4 += __shfl_xor(a4, 8);  a5 += __shfl_xor(a5, 8);        \
    a6 += __shfl_xor(a6, 8);  a7 += __shfl_xor(a7, 8);                                  \
    a0 += __shfl_xor(a0, 16); a1 += __shfl_xor(a1, 16); a2 += __shfl_xor(a2, 16);       \
    a3 += __shfl_xor(a3, 16); a4 += __shfl_xor(a4, 16); a5 += __shfl_xor(a5, 16);       \
    a6 += __shfl_xor(a6, 16); a7 += __shfl_xor(a7, 16);                                 \
    a0 += __shfl_xor(a0, 32); a1 += __shfl_xor(a1, 32); a2 += __shfl_xor(a2, 32);       \
    a3 += __shfl_xor(a3, 32); a4 += __shfl_xor(a4, 32); a5 += __shfl_xor(a5, 32);       \
    a6 += __shfl_xor(a6, 32); a7 += __shfl_xor(a7, 32);

// ---------------- layer A fused: agg(y) -> +b1,relu -> @W2a+b2a -> relu -> h1 bf16

__global__ void __launch_bounds__(512) aggFA_k(
        const u16* __restrict__ yb, const int* __restrict__ off,
        const int* __restrict__ csr, const float* __restrict__ b1,
        const float* __restrict__ W2, const float* __restrict__ b2,
        u16* __restrict__ h1b) {
    __shared__ __align__(16) float sW4[64 * 64];   // swizzled for b128 reads
    __shared__ __align__(16) float su[8][64];
    fill_swz(sW4, W2, threadIdx.x, 512);
    __syncthreads();
    int wid = threadIdx.x >> 6, lane = threadIdx.x & 63;
    float4 b1v0 = ((const float4*)b1)[(lane & 7) * 2];
    float4 b1v1 = ((const float4*)b1)[(lane & 7) * 2 + 1];
    float bb2 = b2[lane];
    int gw = blockIdx.x * 8 + wid;
    const int NW = 1024 * 8;
    for (int n = gw; n < N_NODES; n += NW) {
        AGG_BODY(yb)
        if (lane < 8) {
            float4 u0 = make_float4(fmaxf(a0 + b1v0.x, 0.f), fmaxf(a1 + b1v0.y, 0.f),
                                    fmaxf(a2 + b1v0.z, 0.f), fmaxf(a3 + b1v0.w, 0.f));
            float4 u1 = make_float4(fmaxf(a4 + b1v1.x, 0.f), fmaxf(a5 + b1v1.y, 0.f),
                                    fmaxf(a6 + b1v1.z, 0.f), fmaxf(a7 + b1v1.w, 0.f));
            *(float4*)&su[wid][c << 3] = u0;
            *(float4*)&su[wid][(c << 3) + 4] = u1;
        }
        __builtin_amdgcn_wave_barrier();
        float o = bb2;
#pragma unroll
        for (int c4 = 0; c4 < 16; ++c4) {
            float4 w = *(const float4*)&sW4[(c4 << 8) + (lane << 2)];
            float4 v = *(const float4*)&su[wid][c4 << 2];
            o = fmaf(w.x, v.x, o); o = fmaf(w.y, v.y, o);
            o = fmaf(w.z, v.z, o); o = fmaf(w.w, v.w, o);
        }
        __builtin_amdgcn_wave_barrier();
        h1b[(size_t)n * 64 + lane] = f2bf(fmaxf(o, 0.f));
    }
}

// ---------------- layer B fused: agg(h1) -> @W1b+b1b,relu -> @W2b+b2b -> relu -> h2 bf16

__global__ void __launch_bounds__(512) aggFB_k(
        const u16* __restrict__ h1b, const int* __restrict__ off,
        const int* __restrict__ csr, const float* __restrict__ W1,
        const float* __restrict__ b1, const float* __restrict__ W2,
        const float* __restrict__ b2, u16* __restrict__ h2b) {
    __shared__ __align__(16) float sW14[64 * 64];
    __shared__ __align__(16) float sW24[64 * 64];
    __shared__ __align__(16) float su1[8][64];
    __shared__ __align__(16) float su2[8][64];
    fill_swz(sW14, W1, threadIdx.x, 512);
    fill_swz(sW24, W2, threadIdx.x, 512);
    __syncthreads();
    int wid = threadIdx.x >> 6, lane = threadIdx.x & 63;
    float bb1 = b1[lane], bb2 = b2[lane];
    int gw = blockIdx.x * 8 + wid;
    const int NW = 1024 * 8;
    for (int n = gw; n < N_NODES; n += NW) {
        AGG_BODY(h1b)
        if (lane < 8) {
            *(float4*)&su1[wid][c << 3] = make_float4(a0, a1, a2, a3);
            *(float4*)&su1[wid][(c << 3) + 4] = make_float4(a4, a5, a6, a7);
        }
        __builtin_amdgcn_wave_barrier();
        float u = bb1;
#pragma unroll
        for (int c4 = 0; c4 < 16; ++c4) {
            float4 w = *(const float4*)&sW14[(c4 << 8) + (lane << 2)];
            float4 v = *(const float4*)&su1[wid][c4 << 2];
            u = fmaf(w.x, v.x, u); u = fmaf(w.y, v.y, u);
            u = fmaf(w.z, v.z, u); u = fmaf(w.w, v.w, u);
        }
        u = fmaxf(u, 0.f);
        __builtin_amdgcn_wave_barrier();
        su2[wid][lane] = u;
        __builtin_amdgcn_wave_barrier();
        float o = bb2;
#pragma unroll
        for (int c4 = 0; c4 < 16; ++c4) {
            float4 w = *(const float4*)&sW24[(c4 << 8) + (lane << 2)];
            float4 v = *(const float4*)&su2[wid][c4 << 2];
            o = fmaf(w.x, v.x, o); o = fmaf(w.y, v.y, o);
            o = fmaf(w.z, v.z, o); o = fmaf(w.w, v.w, o);
        }
        __builtin_amdgcn_wave_barrier();
        h2b[(size_t)n * 64 + lane] = f2bf(fmaxf(o, 0.f));
    }
}

// ---------------- classifier + log_softmax ----------------

__global__ void cls_k(const u16* __restrict__ h2b, const float* __restrict__ Wl,
                      const float* __restrict__ bl, float* __restrict__ out) {
    __shared__ float sW[64 * N_CLASSES];
    __shared__ float sb[16];
    for (int i = threadIdx.x; i < 64 * N_CLASSES; i += 256) sW[i] = Wl[i];
    if (threadIdx.x < N_CLASSES) sb[threadIdx.x] = bl[threadIdx.x];
    __syncthreads();
    int n = blockIdx.x * 256 + threadIdx.x;
    if (n >= N_NODES) return;
    float logit[N_CLASSES];
#pragma unroll
    for (int k = 0; k < N_CLASSES; ++k) logit[k] = sb[k];
    const ushort4* row = (const ushort4*)(h2b + (size_t)n * 64);
#pragma unroll
    for (int i = 0; i < 16; ++i) {
        ushort4 q = row[i];
        float v0 = u2f(((u32)q.x) << 16), v1 = u2f(((u32)q.y) << 16);
        float v2 = u2f(((u32)q.z) << 16), v3 = u2f(((u32)q.w) << 16);
#pragma unroll
        for (int k = 0; k < N_CLASSES; ++k) {
            logit[k] = fmaf(v0, sW[(i * 4 + 0) * N_CLASSES + k], logit[k]);
            logit[k] = fmaf(v1, sW[(i * 4 + 1) * N_CLASSES + k], logit[k]);
            logit[k] = fmaf(v2, sW[(i * 4 + 2) * N_CLASSES + k], logit[k]);
            logit[k] = fmaf(v3, sW[(i * 4 + 3) * N_CLASSES + k], logit[k]);
        }
    }
    float m = logit[0];
#pragma unroll
    for (int k = 1; k < N_CLASSES; ++k) m = fmaxf(m, logit[k]);
    float s = 0.f;
#pragma unroll
    for (int k = 0; k < N_CLASSES; ++k) s = s + __expf(logit[k] - m);
    float ls = __logf(s);
#pragma unroll
    for (int k = 0; k < N_CLASSES; ++k) out[(size_t)n * N_CLASSES + k] = logit[k] - m - ls;
}

// ---------------- launch ----------------

extern "C" void kernel_launch(void* const* d_in, const int* in_sizes, int n_in,
                              void* d_out, int out_size, void* d_ws, size_t ws_size,
                              hipStream_t stream) {
    const float* x   = (const float*)d_in[0];
    const int*   ei  = (const int*)d_in[1];
    const int*   src = ei;
    const int*   dst = ei + N_EDGES;
    const float* W1a = (const float*)d_in[2];
    const float* b1a = (const float*)d_in[3];
    const float* W2a = (const float*)d_in[4];
    const float* b2a = (const float*)d_in[5];
    const float* W1b = (const float*)d_in[6];
    const float* b1b = (const float*)d_in[7];
    const float* W2b = (const float*)d_in[8];
    const float* b2b = (const float*)d_in[9];
    const float* Wl  = (const float*)d_in[10];
    const float* bl  = (const float*)d_in[11];
    float* out = (float*)d_out;

    char* ws = (char*)d_ws;
    size_t o = 0;
    auto alloc = [&](size_t bytes) -> void* {
        o = (o + 255) & ~(size_t)255;
        void* p = ws + o;
        o += bytes;
        return p;
    };
    int* bcnt  = (int*)alloc((size_t)NB * 4);
    int* bbase = (int*)alloc((size_t)NB * 4);
    int* off   = (int*)alloc((size_t)(N_NODES + 1) * 4);
    u32* stage = (u32*)alloc((size_t)NB * BCAP * 4);     // 16.0 MB (packed)
    int* csr   = (int*)alloc((size_t)N_EDGES * 4);       // 12.8 MB
    u16* yb    = (u16*)alloc((size_t)N_NODES * 64 * 2);  // 12.8 MB
    u16* h1b   = (u16*)alloc((size_t)N_NODES * 64 * 2);
    u16* h2b   = (u16*)alloc((size_t)N_NODES * 64 * 2);

    hipMemsetAsync(bcnt, 0, (size_t)NB * 4, stream);

    const int nA = (N_EDGES + CHUNK - 1) / CHUNK;        // 196
    passA_k<<<nA, 1024, 0, stream>>>(src, dst, bcnt, stage);
    bscan_k<<<1, 512, 0, stream>>>(bcnt, bbase, off);
    passB_k<<<NB, 1024, 0, stream>>>(bcnt, bbase, stage, off, csr);

    lin1_k <<<1024, 512, 0, stream>>>(x, W1a, yb);
    aggFA_k<<<1024, 512, 0, stream>>>(yb, off, csr, b1a, W2a, b2a, h1b);
    aggFB_k<<<1024, 512, 0, stream>>>(h1b, off, csr, W1b, b1b, W2b, b2b, h2b);
    cls_k  <<<(N_NODES + 255) / 256, 256, 0, stream>>>(h2b, Wl, bl, out);
}

// Round 6
// 373.953 us; speedup vs baseline: 3.1252x; 1.0870x over previous
//
#include <hip/hip_runtime.h>
#include <hip/hip_bf16.h>

#define N_NODES 100000
#define N_EDGES 3200000
#define IN_CH 128
#define HID 64
#define N_CLASSES 10

// bucketized CSR build
#define NB 391          // ceil(100000/256) buckets of 256 nodes
#define NPB 256
#define BCAP 10240      // mean 8192, sigma~90
#define CHUNK 8192      // edges per passA block -> 391 blocks (was 196)

typedef unsigned short u16;
typedef unsigned int u32;

static __device__ __forceinline__ float u2f(u32 u) {
    union { u32 i; float f; } v; v.i = u; return v.f;
}
static __device__ __forceinline__ u16 f2bf(float f) {
    __hip_bfloat16 b = __float2bfloat16(f);   // RNE
    return *(u16*)&b;
}

// ---------------- CSR build: pass A — bucket partition (packed u32 stage) ----------------

__global__ void __launch_bounds__(1024) passA_k(
        const int* __restrict__ src, const int* __restrict__ dst,
        int* __restrict__ bcnt, u32* __restrict__ stage) {
    __shared__ int lh[NB];
    __shared__ int lb[NB];
    for (int i = threadIdx.x; i < NB; i += 1024) lh[i] = 0;
    __syncthreads();
    int e0 = blockIdx.x * CHUNK;
#pragma unroll
    for (int k = 0; k < CHUNK / 1024; ++k) {
        int e = e0 + k * 1024 + threadIdx.x;
        if (e < N_EDGES) atomicAdd(&lh[dst[e] >> 8], 1);
    }
    __syncthreads();
    for (int i = threadIdx.x; i < NB; i += 1024) {
        lb[i] = atomicAdd(&bcnt[i], lh[i]);
        lh[i] = 0;
    }
    __syncthreads();
#pragma unroll
    for (int k = 0; k < CHUNK / 1024; ++k) {
        int e = e0 + k * 1024 + threadIdx.x;
        if (e < N_EDGES) {
            int d = dst[e];
            int b = d >> 8;
            int p = lb[b] + atomicAdd(&lh[b], 1);
            if (p < BCAP) stage[(size_t)b * BCAP + p] = ((u32)src[e] << 8) | (u32)(d & 255);
        }
    }
}

// ---------------- bucket scan ----------------

__global__ void bscan_k(const int* __restrict__ bcnt, int* __restrict__ bbase,
                        int* __restrict__ off) {
    __shared__ int s[512];
    int tid = threadIdx.x;
    int v = (tid < NB) ? min(bcnt[tid], BCAP) : 0;
    s[tid] = v;
    __syncthreads();
    for (int o = 1; o < 512; o <<= 1) {
        int t = (tid >= o) ? s[tid - o] : 0;
        __syncthreads();
        s[tid] += t;
        __syncthreads();
    }
    if (tid < NB) bbase[tid] = s[tid] - v;
    if (tid == NB - 1) off[N_NODES] = s[tid];
}

// ---------------- pass B — per-bucket CSR in LDS, coalesced writeout ----------------

__global__ void __launch_bounds__(1024) passB_k(
        const int* __restrict__ bcnt, const int* __restrict__ bbase,
        const u32* __restrict__ stage, int* __restrict__ off,
        int* __restrict__ csr) {
    __shared__ int ldeg[NPB];
    __shared__ int loff[NPB + 1];
    __shared__ int lcur[NPB];
    __shared__ int img[BCAP];
    int b = blockIdx.x;
    int nb = min(bcnt[b], BCAP);
    int base = bbase[b];
    const u32* st = stage + (size_t)b * BCAP;
    int tid = threadIdx.x;
    if (tid < NPB) ldeg[tid] = 0;
    __syncthreads();
    for (int i = tid; i < nb; i += 1024) atomicAdd(&ldeg[st[i] & 255u], 1);
    __syncthreads();
    if (tid < NPB) lcur[tid] = ldeg[tid];
    __syncthreads();
    for (int o = 1; o < NPB; o <<= 1) {
        int t = (tid < NPB && tid >= o) ? lcur[tid - o] : 0;
        __syncthreads();
        if (tid < NPB) lcur[tid] += t;
        __syncthreads();
    }
    if (tid < NPB) loff[tid + 1] = lcur[tid];
    if (tid == 0) loff[0] = 0;
    __syncthreads();
    if (tid < NPB) {
        int gnode = (b << 8) + tid;
        if (gnode < N_NODES) off[gnode] = base + loff[tid];
        lcur[tid] = loff[tid];
    }
    __syncthreads();
    for (int i = tid; i < nb; i += 1024) {
        u32 pr = st[i];
        int p = atomicAdd(&lcur[pr & 255u], 1);
        img[p] = (int)(pr >> 8);
    }
    __syncthreads();
    for (int i = tid; i < nb; i += 1024) csr[base + i] = img[i];
}

// swizzled weight fill (generic C x 64): sW4[(c>>2)*256 + out*4 + (c&3)] = W[c*64+out]
static __device__ __forceinline__ void fill_swz(float* sW4, const float* __restrict__ W,
                                                int nelem, int tid, int nthr) {
    for (int i = tid; i < nelem; i += nthr) {
        int c = i >> 6, out = i & 63;
        sW4[((c >> 2) << 8) + (out << 2) + (c & 3)] = W[i];
    }
}

// ---------------- y = x @ W1a  (no bias), stored bf16 ----------------
// swizzled weights -> ds_read_b128; 32 b128 weight reads + 32 broadcast reads per node.

__global__ void __launch_bounds__(512) lin1_k(
        const float* __restrict__ x, const float* __restrict__ W1,
        u16* __restrict__ yb) {
    __shared__ __align__(16) float sW4[IN_CH * 64];   // 32 KB swizzled
    __shared__ __align__(16) float srow[8][IN_CH];
    fill_swz(sW4, W1, IN_CH * 64, threadIdx.x, 512);
    __syncthreads();
    int wid = threadIdx.x >> 6, lane = threadIdx.x & 63;
    int gw = blockIdx.x * 8 + wid;
    const int NW = 1024 * 8;
    for (int n = gw; n < N_NODES; n += NW) {
        srow[wid][lane]      = x[(size_t)n * IN_CH + lane];
        srow[wid][64 + lane] = x[(size_t)n * IN_CH + 64 + lane];
        __builtin_amdgcn_wave_barrier();
        float acc = 0.f;
#pragma unroll
        for (int c4 = 0; c4 < IN_CH / 4; ++c4) {
            float4 w = *(const float4*)&sW4[(c4 << 8) + (lane << 2)];
            float4 r = *(const float4*)&srow[wid][c4 << 2];
            acc = fmaf(r.x, w.x, acc); acc = fmaf(r.y, w.y, acc);
            acc = fmaf(r.z, w.z, acc); acc = fmaf(r.w, w.w, acc);
        }
        __builtin_amdgcn_wave_barrier();
        yb[(size_t)n * 64 + lane] = f2bf(acc);
    }
}

// 8-edge gather step: lane l -> edge slot g=l>>3, channel octet c=l&7.
// unroll 4: four independent csr+row load chains in flight.
#define AGG_BODY(TAB)                                                                   \
    const char* tb = (const char*)(TAB);                                                \
    int g = lane >> 3, c = lane & 7;                                                    \
    int coff = c << 4; /* byte offset in 128B row */                                    \
    float a0, a1, a2, a3, a4, a5, a6, a7;                                               \
    {   uint4 dS = *(const uint4*)(tb + (size_t)n * 128 + coff);                        \
        u32 sm = (g == 0) ? 0xffffffffu : 0u;                                           \
        dS.x &= sm; dS.y &= sm; dS.z &= sm; dS.w &= sm;                                 \
        a0 = u2f(dS.x << 16); a1 = u2f(dS.x & 0xffff0000u);                             \
        a2 = u2f(dS.y << 16); a3 = u2f(dS.y & 0xffff0000u);                             \
        a4 = u2f(dS.z << 16); a5 = u2f(dS.z & 0xffff0000u);                             \
        a6 = u2f(dS.w << 16); a7 = u2f(dS.w & 0xffff0000u); }                           \
    int e = off[n], e1 = off[n + 1];                                                    \
    int nfull = (e1 - e) >> 3;                                                          \
    _Pragma("unroll 4")                                                                 \
    for (int it = 0; it < nfull; ++it) {                                                \
        int s = csr[e + g];                                                             \
        uint4 d = *(const uint4*)(tb + (size_t)s * 128 + coff);                         \
        a0 += u2f(d.x << 16); a1 += u2f(d.x & 0xffff0000u);                             \
        a2 += u2f(d.y << 16); a3 += u2f(d.y & 0xffff0000u);                             \
        a4 += u2f(d.z << 16); a5 += u2f(d.z & 0xffff0000u);                             \
        a6 += u2f(d.w << 16); a7 += u2f(d.w & 0xffff0000u);                             \
        e += 8;                                                                         \
    }                                                                                   \
    int rem = e1 - e;                                                                   \
    if (rem > 0) {                                                                      \
        int s = csr[e + min(g, rem - 1)];                                               \
        u32 m = (g < rem) ? 0xffffffffu : 0u;                                           \
        uint4 d = *(const uint4*)(tb + (size_t)s * 128 + coff);                         \
        d.x &= m; d.y &= m; d.z &= m; d.w &= m;                                         \
        a0 += u2f(d.x << 16); a1 += u2f(d.x & 0xffff0000u);                             \
        a2 += u2f(d.y << 16); a3 += u2f(d.y & 0xffff0000u);                             \
        a4 += u2f(d.z << 16); a5 += u2f(d.z & 0xffff0000u);                             \
        a6 += u2f(d.w << 16); a7 += u2f(d.w & 0xffff0000u);                             \
    }                                                                                   \
    /* reduce across the 8 edge groups (xor 8,16,32) */                                 \
    a0 += __shfl_xor(a0, 8);  a1 += __shfl_xor(a1, 8);  a2 += __shfl_xor(a2, 8);        \
    a3 += __shfl_xor(a3, 8);  a4 += __shfl_xor(a4, 8);  a5 += __shfl_xor(a5, 8);        \
    a6 += __shfl_xor(a6, 8);  a7 += __shfl_xor(a7, 8);                                  \
    a0 += __shfl_xor(a0, 16); a1 += __shfl_xor(a1, 16); a2 += __shfl_xor(a2, 16);       \
    a3 += __shfl_xor(a3, 16); a4 += __shfl_xor(a4, 16); a5 += __shfl_xor(a5, 16);       \
    a6 += __shfl_xor(a6, 16); a7 += __shfl_xor(a7, 16);                                 \
    a0 += __shfl_xor(a0, 32); a1 += __shfl_xor(a1, 32); a2 += __shfl_xor(a2, 32);       \
    a3 += __shfl_xor(a3, 32); a4 += __shfl_xor(a4, 32); a5 += __shfl_xor(a5, 32);       \
    a6 += __shfl_xor(a6, 32); a7 += __shfl_xor(a7, 32);

// ---------------- layer A fused: agg(y) -> +b1,relu -> @W2a+b2a -> relu -> h1 bf16

__global__ void __launch_bounds__(512) aggFA_k(
        const u16* __restrict__ yb, const int* __restrict__ off,
        const int* __restrict__ csr, const float* __restrict__ b1,
        const float* __restrict__ W2, const float* __restrict__ b2,
        u16* __restrict__ h1b) {
    __shared__ __align__(16) float sW4[64 * 64];   // swizzled for b128 reads
    __shared__ __align__(16) float su[8][64];
    fill_swz(sW4, W2, 64 * 64, threadIdx.x, 512);
    __syncthreads();
    int wid = threadIdx.x >> 6, lane = threadIdx.x & 63;
    float4 b1v0 = ((const float4*)b1)[(lane & 7) * 2];
    float4 b1v1 = ((const float4*)b1)[(lane & 7) * 2 + 1];
    float bb2 = b2[lane];
    int gw = blockIdx.x * 8 + wid;
    const int NW = 1024 * 8;
    for (int n = gw; n < N_NODES; n += NW) {
        AGG_BODY(yb)
        if (lane < 8) {
            float4 u0 = make_float4(fmaxf(a0 + b1v0.x, 0.f), fmaxf(a1 + b1v0.y, 0.f),
                                    fmaxf(a2 + b1v0.z, 0.f), fmaxf(a3 + b1v0.w, 0.f));
            float4 u1 = make_float4(fmaxf(a4 + b1v1.x, 0.f), fmaxf(a5 + b1v1.y, 0.f),
                                    fmaxf(a6 + b1v1.z, 0.f), fmaxf(a7 + b1v1.w, 0.f));
            *(float4*)&su[wid][c << 3] = u0;
            *(float4*)&su[wid][(c << 3) + 4] = u1;
        }
        __builtin_amdgcn_wave_barrier();
        float o = bb2;
#pragma unroll
        for (int c4 = 0; c4 < 16; ++c4) {
            float4 w = *(const float4*)&sW4[(c4 << 8) + (lane << 2)];
            float4 v = *(const float4*)&su[wid][c4 << 2];
            o = fmaf(w.x, v.x, o); o = fmaf(w.y, v.y, o);
            o = fmaf(w.z, v.z, o); o = fmaf(w.w, v.w, o);
        }
        __builtin_amdgcn_wave_barrier();
        h1b[(size_t)n * 64 + lane] = f2bf(fmaxf(o, 0.f));
    }
}

// ---------------- layer B fused: agg(h1) -> @W1b+b1b,relu -> @W2b+b2b -> relu -> h2 bf16

__global__ void __launch_bounds__(512) aggFB_k(
        const u16* __restrict__ h1b, const int* __restrict__ off,
        const int* __restrict__ csr, const float* __restrict__ W1,
        const float* __restrict__ b1, const float* __restrict__ W2,
        const float* __restrict__ b2, u16* __restrict__ h2b) {
    __shared__ __align__(16) float sW14[64 * 64];
    __shared__ __align__(16) float sW24[64 * 64];
    __shared__ __align__(16) float su1[8][64];
    __shared__ __align__(16) float su2[8][64];
    fill_swz(sW14, W1, 64 * 64, threadIdx.x, 512);
    fill_swz(sW24, W2, 64 * 64, threadIdx.x, 512);
    __syncthreads();
    int wid = threadIdx.x >> 6, lane = threadIdx.x & 63;
    float bb1 = b1[lane], bb2 = b2[lane];
    int gw = blockIdx.x * 8 + wid;
    const int NW = 1024 * 8;
    for (int n = gw; n < N_NODES; n += NW) {
        AGG_BODY(h1b)
        if (lane < 8) {
            *(float4*)&su1[wid][c << 3] = make_float4(a0, a1, a2, a3);
            *(float4*)&su1[wid][(c << 3) + 4] = make_float4(a4, a5, a6, a7);
        }
        __builtin_amdgcn_wave_barrier();
        float u = bb1;
#pragma unroll
        for (int c4 = 0; c4 < 16; ++c4) {
            float4 w = *(const float4*)&sW14[(c4 << 8) + (lane << 2)];
            float4 v = *(const float4*)&su1[wid][c4 << 2];
            u = fmaf(w.x, v.x, u); u = fmaf(w.y, v.y, u);
            u = fmaf(w.z, v.z, u); u = fmaf(w.w, v.w, u);
        }
        u = fmaxf(u, 0.f);
        __builtin_amdgcn_wave_barrier();
        su2[wid][lane] = u;
        __builtin_amdgcn_wave_barrier();
        float o = bb2;
#pragma unroll
        for (int c4 = 0; c4 < 16; ++c4) {
            float4 w = *(const float4*)&sW24[(c4 << 8) + (lane << 2)];
            float4 v = *(const float4*)&su2[wid][c4 << 2];
            o = fmaf(w.x, v.x, o); o = fmaf(w.y, v.y, o);
            o = fmaf(w.z, v.z, o); o = fmaf(w.w, v.w, o);
        }
        __builtin_amdgcn_wave_barrier();
        h2b[(size_t)n * 64 + lane] = f2bf(fmaxf(o, 0.f));
    }
}

// ---------------- classifier + log_softmax ----------------

__global__ void cls_k(const u16* __restrict__ h2b, const float* __restrict__ Wl,
                      const float* __restrict__ bl, float* __restrict__ out) {
    __shared__ float sW[64 * N_CLASSES];
    __shared__ float sb[16];
    for (int i = threadIdx.x; i < 64 * N_CLASSES; i += 256) sW[i] = Wl[i];
    if (threadIdx.x < N_CLASSES) sb[threadIdx.x] = bl[threadIdx.x];
    __syncthreads();
    int n = blockIdx.x * 256 + threadIdx.x;
    if (n >= N_NODES) return;
    float logit[N_CLASSES];
#pragma unroll
    for (int k = 0; k < N_CLASSES; ++k) logit[k] = sb[k];
    const ushort4* row = (const ushort4*)(h2b + (size_t)n * 64);
#pragma unroll
    for (int i = 0; i < 16; ++i) {
        ushort4 q = row[i];
        float v0 = u2f(((u32)q.x) << 16), v1 = u2f(((u32)q.y) << 16);
        float v2 = u2f(((u32)q.z) << 16), v3 = u2f(((u32)q.w) << 16);
#pragma unroll
        for (int k = 0; k < N_CLASSES; ++k) {
            logit[k] = fmaf(v0, sW[(i * 4 + 0) * N_CLASSES + k], logit[k]);
            logit[k] = fmaf(v1, sW[(i * 4 + 1) * N_CLASSES + k], logit[k]);
            logit[k] = fmaf(v2, sW[(i * 4 + 2) * N_CLASSES + k], logit[k]);
            logit[k] = fmaf(v3, sW[(i * 4 + 3) * N_CLASSES + k], logit[k]);
        }
    }
    float m = logit[0];
#pragma unroll
    for (int k = 1; k < N_CLASSES; ++k) m = fmaxf(m, logit[k]);
    float s = 0.f;
#pragma unroll
    for (int k = 0; k < N_CLASSES; ++k) s = s + __expf(logit[k] - m);
    float ls = __logf(s);
#pragma unroll
    for (int k = 0; k < N_CLASSES; ++k) out[(size_t)n * N_CLASSES + k] = logit[k] - m - ls;
}

// ---------------- launch ----------------

extern "C" void kernel_launch(void* const* d_in, const int* in_sizes, int n_in,
                              void* d_out, int out_size, void* d_ws, size_t ws_size,
                              hipStream_t stream) {
    const float* x   = (const float*)d_in[0];
    const int*   ei  = (const int*)d_in[1];
    const int*   src = ei;
    const int*   dst = ei + N_EDGES;
    const float* W1a = (const float*)d_in[2];
    const float* b1a = (const float*)d_in[3];
    const float* W2a = (const float*)d_in[4];
    const float* b2a = (const float*)d_in[5];
    const float* W1b = (const float*)d_in[6];
    const float* b1b = (const float*)d_in[7];
    const float* W2b = (const float*)d_in[8];
    const float* b2b = (const float*)d_in[9];
    const float* Wl  = (const float*)d_in[10];
    const float* bl  = (const float*)d_in[11];
    float* out = (float*)d_out;

    char* ws = (char*)d_ws;
    size_t o = 0;
    auto alloc = [&](size_t bytes) -> void* {
        o = (o + 255) & ~(size_t)255;
        void* p = ws + o;
        o += bytes;
        return p;
    };
    int* bcnt  = (int*)alloc((size_t)NB * 4);
    int* bbase = (int*)alloc((size_t)NB * 4);
    int* off   = (int*)alloc((size_t)(N_NODES + 1) * 4);
    u32* stage = (u32*)alloc((size_t)NB * BCAP * 4);     // 16.0 MB (packed)
    int* csr   = (int*)alloc((size_t)N_EDGES * 4);       // 12.8 MB
    u16* yb    = (u16*)alloc((size_t)N_NODES * 64 * 2);  // 12.8 MB
    u16* h1b   = (u16*)alloc((size_t)N_NODES * 64 * 2);
    u16* h2b   = (u16*)alloc((size_t)N_NODES * 64 * 2);

    hipMemsetAsync(bcnt, 0, (size_t)NB * 4, stream);

    const int nA = (N_EDGES + CHUNK - 1) / CHUNK;        // 391
    passA_k<<<nA, 1024, 0, stream>>>(src, dst, bcnt, stage);
    bscan_k<<<1, 512, 0, stream>>>(bcnt, bbase, off);
    passB_k<<<NB, 1024, 0, stream>>>(bcnt, bbase, stage, off, csr);

    lin1_k <<<1024, 512, 0, stream>>>(x, W1a, yb);
    aggFA_k<<<1024, 512, 0, stream>>>(yb, off, csr, b1a, W2a, b2a, h1b);
    aggFB_k<<<1024, 512, 0, stream>>>(h1b, off, csr, W1b, b1b, W2b, b2b, h2b);
    cls_k  <<<(N_NODES + 255) / 256, 256, 0, stream>>>(h2b, Wl, bl, out);
}